// Round 3
// baseline (669.710 us; speedup 1.0000x reference)
//
#include <hip/hip_runtime.h>
#include <hip/hip_bf16.h>
#include <math.h>

#define N_ENT 200000
#define DD 256
#define NB 64
#define NK 21
#define PROJ 200
#define NS 5
#define NQ 1024
#define PADID (N_ENT - 1)
#define LOGMIN -69.07755279f

// ---------------- K0: wT[j][d] = attn_w[d][j] (so K1 reads are coalesced)
__global__ __launch_bounds__(256) void k_transpose(const float* __restrict__ w,
                                                   float* __restrict__ wT) {
  int j = blockIdx.x, d = threadIdx.x;
  wT[j * DD + d] = w[d * DD + j];
}

// ---------------- K1: t2 rows = (ent[tail]-ent[head]) @ attn_w.T + attn_b
// rows 0..1023 = queries, 1024..1028 = supports
__global__ __launch_bounds__(256) void k_t2(const int* __restrict__ qh, const int* __restrict__ qt,
                                            const int* __restrict__ sh, const int* __restrict__ st,
                                            const float* __restrict__ ent, const float* __restrict__ wT,
                                            const float* __restrict__ ab, float* __restrict__ t2) {
  int r = blockIdx.x, d = threadIdx.x;
  int head, tail;
  if (r < NQ) { head = qh[r]; tail = qt[r]; }
  else        { head = sh[r - NQ]; tail = st[r - NQ]; }
  __shared__ float tv[DD];
  tv[d] = ent[(size_t)tail * DD + d] - ent[(size_t)head * DD + d];
  __syncthreads();
  float acc = ab[d];
  #pragma unroll 8
  for (int j = 0; j < DD; ++j) acc += tv[j] * wT[j * DD + d];
  t2[r * DD + d] = acc;
}

// ---------------- K2: q_att[q][n] = t2[q] . ent_emb[q_nb[q][n]]
__global__ __launch_bounds__(256) void k_qatt(const int* __restrict__ qt, const int* __restrict__ ed,
                                              const float* __restrict__ ent, const float* __restrict__ t2,
                                              float* __restrict__ qatt) {
  int q = blockIdx.x, tid = threadIdx.x;
  __shared__ float t2s[DD];
  __shared__ int nbs[NB];
  t2s[tid] = t2[q * DD + tid];
  if (tid < NB) nbs[tid] = ed[((size_t)qt[q] * NB + tid) * 2 + 1];
  __syncthreads();
  int n = tid >> 2, seg = tid & 3;
  const float4* er = (const float4*)(ent + (size_t)nbs[n] * DD + seg * 64);
  const float4* ts = (const float4*)(t2s + seg * 64);
  float s = 0.f;
  #pragma unroll
  for (int j = 0; j < 16; ++j) {
    float4 v = er[j], t = ts[j];
    s += v.x * t.x + v.y * t.y + v.z * t.z + v.w * t.w;
  }
  s += __shfl_xor(s, 1);
  s += __shfl_xor(s, 2);
  if (seg == 0) qatt[q * NB + n] = s;
}

// ---------------- K3: B[m][k] = l2norm(rel_emb[s_nb[s][mm]]) * s_att[s][mm], m = s*64+mm
__global__ __launch_bounds__(256) void k_support(const int* __restrict__ st, const int* __restrict__ ed,
                                                 const float* __restrict__ ent, const float* __restrict__ rel,
                                                 const float* __restrict__ t2, float* __restrict__ Ball) {
  int s = blockIdx.x, tid = threadIdx.x;
  __shared__ float t2s[DD];
  __shared__ int nbs[NB];
  __shared__ float att[NB];
  t2s[tid] = t2[(NQ + s) * DD + tid];
  if (tid < NB) nbs[tid] = ed[((size_t)st[s] * NB + tid) * 2 + 1];
  __syncthreads();
  int n = tid >> 2, seg = tid & 3;
  const float4* er = (const float4*)(ent + (size_t)nbs[n] * DD + seg * 64);
  const float4* ts = (const float4*)(t2s + seg * 64);
  float a = 0.f;
  #pragma unroll
  for (int j = 0; j < 16; ++j) {
    float4 v = er[j], t = ts[j];
    a += v.x * t.x + v.y * t.y + v.z * t.z + v.w * t.w;
  }
  a += __shfl_xor(a, 1);
  a += __shfl_xor(a, 2);
  if (seg == 0) att[n] = a;
  const float4* rr = (const float4*)(rel + (size_t)nbs[n] * DD + seg * 64);
  float4 buf[16];
  float ss = 0.f;
  #pragma unroll
  for (int j = 0; j < 16; ++j) {
    float4 v = rr[j]; buf[j] = v;
    ss += v.x * v.x + v.y * v.y + v.z * v.z + v.w * v.w;
  }
  ss += __shfl_xor(ss, 1);
  ss += __shfl_xor(ss, 2);
  __syncthreads();
  float scale = att[n] / fmaxf(sqrtf(ss), 1e-12f);
  float4* ob = (float4*)(Ball + ((size_t)s * NB + n) * DD + seg * 64);
  #pragma unroll
  for (int j = 0; j < 16; ++j) {
    float4 v = buf[j];
    ob[j] = make_float4(v.x * scale, v.y * scale, v.z * scale, v.w * scale);
  }
}

// ---------------- K4: per-q fused GEMM (64n x 320m x 256k) + pool + kernel-density + MLP + max_s
#define APAD 260   // 260 % 8 == 4 words -> a-reads 2-way conflict (free), float4-aligned rows
#define BPAD 36    // 36 % 32 == 4 -> b-reads 2-way conflict (free), float4-aligned rows
#define KC 32
__global__ __launch_bounds__(256, 1) void k_main(
    const int* __restrict__ qt, const int* __restrict__ ed,
    const float* __restrict__ rel, const float* __restrict__ Ball,
    const float* __restrict__ qatt,
    const float* __restrict__ d1w, const float* __restrict__ d1b,
    const float* __restrict__ d2w, const float* __restrict__ d2b,
    float* __restrict__ out) {
  int q = blockIdx.x, tid = threadIdx.x;
  int tj = tid & 15, ti = tid >> 4;
  __shared__ float A[NB * APAD];        // 66,560 B  (q_e rows, row-major [n][k])
  __shared__ float Bl[320 * BPAD];      // 46,080 B  (B chunk, [m][kc..kc+31])
  __shared__ float att[NB], msk[NB];
  __shared__ float smax[NB * 16], smin[NB * 16];
  __shared__ float pol[NB];
  __shared__ float te[NK + 3];
  __shared__ float wred[4];
  __shared__ int nbs[NB];
  // total ~122 KB static LDS -> 1 block/CU on gfx950 (160 KB)

  if (tid < NB) {
    int nb = ed[((size_t)qt[q] * NB + tid) * 2 + 1];
    nbs[tid] = nb;
    att[tid] = qatt[q * NB + tid];
    msk[tid] = (nb != PADID) ? 0.01f : 0.0f;  // fold the 0.01 scale into the mask
  }
  __syncthreads();
  {
    // gather + l2-normalize q_e rows into LDS A
    int n = tid >> 2, seg = tid & 3;
    const float4* rr = (const float4*)(rel + (size_t)nbs[n] * DD + seg * 64);
    float4 buf[16];
    float ss = 0.f;
    #pragma unroll
    for (int j = 0; j < 16; ++j) {
      float4 v = rr[j]; buf[j] = v;
      ss += v.x * v.x + v.y * v.y + v.z * v.z + v.w * v.w;
    }
    ss += __shfl_xor(ss, 1);
    ss += __shfl_xor(ss, 2);
    float inv = 1.0f / fmaxf(sqrtf(ss), 1e-12f);
    float4* ar = (float4*)(A + n * APAD + seg * 64);
    #pragma unroll
    for (int j = 0; j < 16; ++j) {
      float4 v = buf[j];
      ar[j] = make_float4(v.x * inv, v.y * inv, v.z * inv, v.w * inv);
    }
  }

  float acc[4][20];
  #pragma unroll
  for (int i = 0; i < 4; ++i)
    #pragma unroll
    for (int j = 0; j < 20; ++j) acc[i][j] = 0.f;

  // thread (ti,tj): rows n = ti*4+i, cols m = tj + 16*j  (j = 4*s + jj -> s-aligned)
  for (int kc = 0; kc < DD; kc += KC) {
    __syncthreads();
    #pragma unroll
    for (int i = 0; i < 10; ++i) {     // stage B chunk: 320 rows x 32 k
      int c = tid + i * 256;
      int m = c >> 3, kk2 = (c & 7) << 2;
      float4 v = *(const float4*)(Ball + (size_t)m * DD + kc + kk2);
      *(float4*)(Bl + m * BPAD + kk2) = v;
    }
    __syncthreads();
    #pragma unroll
    for (int k2 = 0; k2 < KC; k2 += 2) {
      float2 a2[4], b2[20];
      #pragma unroll
      for (int i = 0; i < 4; ++i)
        a2[i] = *(const float2*)(A + (ti * 4 + i) * APAD + kc + k2);
      #pragma unroll
      for (int j = 0; j < 20; ++j)
        b2[j] = *(const float2*)(Bl + (tj + 16 * j) * BPAD + k2);
      #pragma unroll
      for (int i = 0; i < 4; ++i)
        #pragma unroll
        for (int j = 0; j < 20; ++j)
          acc[i][j] = fmaf(a2[i].y, b2[j].y, fmaf(a2[i].x, b2[j].x, acc[i][j]));
    }
  }

  float lmax = -3.0e38f;  // only tid 0's copy is used
  #pragma unroll
  for (int s5 = 0; s5 < NS; ++s5) {
    __syncthreads();
    #pragma unroll
    for (int i = 0; i < 4; ++i) {
      float mx = -3.0e38f, mn = 3.0e38f;
      #pragma unroll
      for (int jj = 0; jj < 4; ++jj) {
        float v = acc[i][4 * s5 + jj];
        mx = fmaxf(mx, v); mn = fminf(mn, v);
      }
      smax[(ti * 4 + i) * 16 + tj] = mx;
      smin[(ti * 4 + i) * 16 + tj] = mn;
    }
    __syncthreads();
    if (tid < NB) {
      float mx = -3.0e38f, mn = 3.0e38f;
      #pragma unroll
      for (int t = 0; t < 16; ++t) {
        mx = fmaxf(mx, smax[tid * 16 + t]);
        mn = fminf(mn, smin[tid * 16 + t]);
      }
      float qa = att[tid];
      // pool = max_m(dot*satt*qatt): qatt constant over m -> sign-select max/min
      pol[tid] = (qa >= 0.f) ? qa * mx : qa * mn;
    }
    __syncthreads();
    if (tid < NK * 8) {
      int k = tid >> 3, np0 = tid & 7;
      double cur = 1.0;                       // replicate _kernel_mus in double
      if (k >= 1) {
        double bq = 1.0 / (double)(NK - 1);
        cur = 1.0 - bq * 0.5;
        for (int i2 = 1; i2 < k; ++i2) cur -= bq;
      }
      float mu = (float)cur;
      float sig = (k == 0) ? 0.001f : 0.1f;
      float s2 = sig * sig;
      float a = 0.f;
      for (int n = np0; n < NB; n += 8) {
        float dd = pol[n] - mu;
        float x = dd * dd / s2 * 0.5f;
        a += msk[n] * fmaxf(-x, LOGMIN);      // log(clip(exp(-x),1e-30)) == max(-x, ln 1e-30)
      }
      a += __shfl_xor(a, 1);
      a += __shfl_xor(a, 2);
      a += __shfl_xor(a, 4);
      if (np0 == 0) te[k] = a;
    }
    __syncthreads();
    float y = 0.f;
    if (tid < PROJ) {
      float h = d1b[tid];
      #pragma unroll
      for (int k = 0; k < NK; ++k) h += te[k] * d1w[tid * NK + k];
      y = h * d2w[tid];
    }
    #pragma unroll
    for (int off = 1; off < 64; off <<= 1) y += __shfl_xor(y, off);
    if ((tid & 63) == 0) wred[tid >> 6] = y;
    __syncthreads();
    if (tid == 0) {
      float logit = wred[0] + wred[1] + wred[2] + wred[3] + d2b[0];
      lmax = fmaxf(lmax, logit);  // max_s sigmoid(x) == sigmoid(max_s x)
    }
  }
  if (tid == 0) out[q] = 1.0f / (1.0f + expf(-lmax));
}

extern "C" void kernel_launch(void* const* d_in, const int* in_sizes, int n_in,
                              void* d_out, int out_size, void* d_ws, size_t ws_size,
                              hipStream_t stream) {
  const int* sh   = (const int*)d_in[0];
  const int* qh   = (const int*)d_in[1];
  const int* st   = (const int*)d_in[2];
  const int* qt   = (const int*)d_in[3];
  const int* ed   = (const int*)d_in[4];
  // d_in[5] = edge_nums (unused by the reference computation)
  const float* rel = (const float*)d_in[6];
  const float* ent = (const float*)d_in[7];
  const float* aw  = (const float*)d_in[8];
  const float* ab  = (const float*)d_in[9];
  const float* d1w = (const float*)d_in[10];
  const float* d1b = (const float*)d_in[11];
  const float* d2w = (const float*)d_in[12];
  const float* d2b = (const float*)d_in[13];
  float* out = (float*)d_out;

  float* ws   = (float*)d_ws;
  float* wT   = ws;                 // 65,536 f
  float* t2   = wT + 65536;         // 1029*256 = 263,424 f
  float* Ball = t2 + 263424;        // 320*256 = 81,920 f
  float* qatt = Ball + 81920;       // 65,536 f   (total ~1.9 MB of ws)

  k_transpose<<<DD, DD, 0, stream>>>(aw, wT);
  k_t2<<<NQ + NS, DD, 0, stream>>>(qh, qt, sh, st, ent, wT, ab, t2);
  k_qatt<<<NQ, DD, 0, stream>>>(qt, ed, ent, t2, qatt);
  k_support<<<NS, DD, 0, stream>>>(st, ed, ent, rel, t2, Ball);
  k_main<<<NQ, DD, 0, stream>>>(qt, ed, rel, Ball, qatt, d1w, d1b, d2w, d2b, out);
}

// Round 4
// 484.068 us; speedup vs baseline: 1.3835x; 1.3835x over previous
//
#include <hip/hip_runtime.h>
#include <hip/hip_bf16.h>
#include <math.h>

#define N_ENT 200000
#define DD 256
#define NB 64
#define NK 21
#define PROJ 200
#define NS 5
#define NQ 1024
#define PADID (N_ENT - 1)
#define LOGMIN -69.07755279f

typedef short s16x8 __attribute__((ext_vector_type(8)));
typedef float f32x4 __attribute__((ext_vector_type(4)));

__device__ inline unsigned short f2bf(float x) {
  __hip_bfloat16 h = __float2bfloat16(x);
  return __builtin_bit_cast(unsigned short, h);
}

// ---------------- K0: wT[j][d] = attn_w[d][j]
__global__ __launch_bounds__(256) void k_transpose(const float* __restrict__ w,
                                                   float* __restrict__ wT) {
  int j = blockIdx.x, d = threadIdx.x;
  wT[j * DD + d] = w[d * DD + j];
}

// ---------------- K1: t2 rows = (ent[tail]-ent[head]) @ attn_w.T + attn_b
__global__ __launch_bounds__(256) void k_t2(const int* __restrict__ qh, const int* __restrict__ qt,
                                            const int* __restrict__ sh, const int* __restrict__ st,
                                            const float* __restrict__ ent, const float* __restrict__ wT,
                                            const float* __restrict__ ab, float* __restrict__ t2) {
  int r = blockIdx.x, d = threadIdx.x;
  int head, tail;
  if (r < NQ) { head = qh[r]; tail = qt[r]; }
  else        { head = sh[r - NQ]; tail = st[r - NQ]; }
  __shared__ float tv[DD];
  tv[d] = ent[(size_t)tail * DD + d] - ent[(size_t)head * DD + d];
  __syncthreads();
  float acc = ab[d];
  #pragma unroll 8
  for (int j = 0; j < DD; ++j) acc += tv[j] * wT[j * DD + d];
  t2[r * DD + d] = acc;
}

// ---------------- K2: q_att[q][n] = t2[q] . ent_emb[q_nb[q][n]]
__global__ __launch_bounds__(256) void k_qatt(const int* __restrict__ qt, const int* __restrict__ ed,
                                              const float* __restrict__ ent, const float* __restrict__ t2,
                                              float* __restrict__ qatt) {
  int q = blockIdx.x, tid = threadIdx.x;
  __shared__ float t2s[DD];
  __shared__ int nbs[NB];
  t2s[tid] = t2[q * DD + tid];
  if (tid < NB) nbs[tid] = ed[((size_t)qt[q] * NB + tid) * 2 + 1];
  __syncthreads();
  int n = tid >> 2, seg = tid & 3;
  const float4* er = (const float4*)(ent + (size_t)nbs[n] * DD + seg * 64);
  const float4* ts = (const float4*)(t2s + seg * 64);
  float s = 0.f;
  #pragma unroll
  for (int j = 0; j < 16; ++j) {
    float4 v = er[j], t = ts[j];
    s += v.x * t.x + v.y * t.y + v.z * t.z + v.w * t.w;
  }
  s += __shfl_xor(s, 1);
  s += __shfl_xor(s, 2);
  if (seg == 0) qatt[q * NB + n] = s;
}

// ---------------- K3: Bb[m][k] (bf16) = l2norm(rel_emb[s_nb[s][mm]]) * s_att[s][mm]
__global__ __launch_bounds__(256) void k_support(const int* __restrict__ st, const int* __restrict__ ed,
                                                 const float* __restrict__ ent, const float* __restrict__ rel,
                                                 const float* __restrict__ t2,
                                                 unsigned short* __restrict__ Bb) {
  int s = blockIdx.x, tid = threadIdx.x;
  __shared__ float t2s[DD];
  __shared__ int nbs[NB];
  __shared__ float att[NB];
  t2s[tid] = t2[(NQ + s) * DD + tid];
  if (tid < NB) nbs[tid] = ed[((size_t)st[s] * NB + tid) * 2 + 1];
  __syncthreads();
  int n = tid >> 2, seg = tid & 3;
  const float4* er = (const float4*)(ent + (size_t)nbs[n] * DD + seg * 64);
  const float4* ts = (const float4*)(t2s + seg * 64);
  float a = 0.f;
  #pragma unroll
  for (int j = 0; j < 16; ++j) {
    float4 v = er[j], t = ts[j];
    a += v.x * t.x + v.y * t.y + v.z * t.z + v.w * t.w;
  }
  a += __shfl_xor(a, 1);
  a += __shfl_xor(a, 2);
  if (seg == 0) att[n] = a;
  const float4* rr = (const float4*)(rel + (size_t)nbs[n] * DD + seg * 64);
  float4 buf[16];
  float ss = 0.f;
  #pragma unroll
  for (int j = 0; j < 16; ++j) {
    float4 v = rr[j]; buf[j] = v;
    ss += v.x * v.x + v.y * v.y + v.z * v.z + v.w * v.w;
  }
  ss += __shfl_xor(ss, 1);
  ss += __shfl_xor(ss, 2);
  __syncthreads();
  float scale = att[n] / fmaxf(sqrtf(ss), 1e-12f);
  unsigned short* ob = Bb + ((size_t)s * NB + n) * DD + seg * 64;
  #pragma unroll
  for (int j = 0; j < 16; ++j) {
    float4 v = buf[j];
    ob[j * 4 + 0] = f2bf(v.x * scale);
    ob[j * 4 + 1] = f2bf(v.y * scale);
    ob[j * 4 + 2] = f2bf(v.z * scale);
    ob[j * 4 + 3] = f2bf(v.w * scale);
  }
}

// ---------------- K4: MFMA GEMM (64n x 320m x 256k bf16) + pool + KDE + MLP + max_s
// A [64][256] bf16 in LDS (padded stride 264 -> 2-way-conflict-free b128 frag reads).
// B [320][256] bf16 in global (160 KB, L2-resident, shared by all blocks) -> frags loaded
// directly from global, software-pipelined: ZERO barriers in the GEMM loop.
// 4 waves; wave wv owns coltiles {wv, wv+4, ..., wv+16} -> exactly one 16-col tile per support s.
#define AP 264
__global__ __launch_bounds__(256) void k_main(
    const int* __restrict__ qt, const int* __restrict__ ed,
    const float* __restrict__ rel, const unsigned short* __restrict__ Bg,
    const float* __restrict__ qatt,
    const float* __restrict__ d1w, const float* __restrict__ d1b,
    const float* __restrict__ d2w, const float* __restrict__ d2b,
    float* __restrict__ out) {
  int q = blockIdx.x, tid = threadIdx.x;
  int wv = tid >> 6, ln = tid & 63;
  int fr = ln & 15, kb = ln >> 4;   // frag row-in-tile / k-block

  __shared__ __align__(16) unsigned short As[NB * AP];   // 33,792 B
  __shared__ float pmax[NS][4][NB], pmin[NS][4][NB];     // 10,240 B
  __shared__ float att[NB], msk[NB], pol[NB], te[NK + 3], wred[4];
  __shared__ int nbs[NB];
  // ~45 KB LDS -> 3 blocks/CU possible

  if (tid < NB) {
    int nb = ed[((size_t)qt[q] * NB + tid) * 2 + 1];
    nbs[tid] = nb;
    att[tid] = qatt[q * NB + tid];
    msk[tid] = (nb != PADID) ? 0.01f : 0.0f;
  }
  __syncthreads();
  {
    // gather + l2norm q_e rows -> bf16 LDS A
    int n = tid >> 2, seg = tid & 3;
    const float4* rr = (const float4*)(rel + (size_t)nbs[n] * DD + seg * 64);
    float4 buf[16];
    float ss = 0.f;
    #pragma unroll
    for (int j = 0; j < 16; ++j) {
      float4 v = rr[j]; buf[j] = v;
      ss += v.x * v.x + v.y * v.y + v.z * v.z + v.w * v.w;
    }
    ss += __shfl_xor(ss, 1);
    ss += __shfl_xor(ss, 2);
    float inv = 1.0f / fmaxf(sqrtf(ss), 1e-12f);
    unsigned short* ap = As + n * AP + seg * 64;
    #pragma unroll
    for (int j = 0; j < 16; ++j) {
      float4 v = buf[j];
      unsigned int lo = (unsigned int)f2bf(v.x * inv) | ((unsigned int)f2bf(v.y * inv) << 16);
      unsigned int hi = (unsigned int)f2bf(v.z * inv) | ((unsigned int)f2bf(v.w * inv) << 16);
      *(unsigned int*)(ap + j * 4)     = lo;
      *(unsigned int*)(ap + j * 4 + 2) = hi;
    }
  }
  __syncthreads();

  // ---- GEMM: acc[i][j] = rowtile i (i*16 rows), coltile (wv + 4*j) -> support s=j
  f32x4 acc[4][5];
  #pragma unroll
  for (int i = 0; i < 4; ++i)
    #pragma unroll
    for (int j = 0; j < 5; ++j) acc[i][j] = (f32x4){0.f, 0.f, 0.f, 0.f};

  const unsigned short* abase = As + fr * AP + kb * 8;
  const unsigned short* bbase = Bg + ((size_t)(wv * 16 + fr)) * DD + kb * 8;

  s16x8 bcur[5], bnxt[5], afr[4];
  #pragma unroll
  for (int j = 0; j < 5; ++j) bcur[j] = *(const s16x8*)(bbase + (size_t)j * 64 * DD);
  #pragma unroll
  for (int k = 0; k < 8; ++k) {
    #pragma unroll
    for (int i = 0; i < 4; ++i) afr[i] = *(const s16x8*)(abase + i * 16 * AP + k * 32);
    if (k < 7) {
      #pragma unroll
      for (int j = 0; j < 5; ++j)
        bnxt[j] = *(const s16x8*)(bbase + (size_t)j * 64 * DD + (k + 1) * 32);
    }
    #pragma unroll
    for (int i = 0; i < 4; ++i)
      #pragma unroll
      for (int j = 0; j < 5; ++j)
        acc[i][j] = __builtin_amdgcn_mfma_f32_16x16x32_bf16(afr[i], bcur[j], acc[i][j], 0, 0, 0);
    #pragma unroll
    for (int j = 0; j < 5; ++j) bcur[j] = bnxt[j];
  }

  // ---- col-reduce each 16x16 tile: D row = kb*4+reg (n = i*16+that), col = fr (m)
  #pragma unroll
  for (int j = 0; j < 5; ++j) {
    #pragma unroll
    for (int i = 0; i < 4; ++i) {
      f32x4 mx = acc[i][j], mn = acc[i][j];
      #pragma unroll
      for (int off = 1; off < 16; off <<= 1) {
        #pragma unroll
        for (int r2 = 0; r2 < 4; ++r2) {
          mx[r2] = fmaxf(mx[r2], __shfl_xor(mx[r2], off));
          mn[r2] = fminf(mn[r2], __shfl_xor(mn[r2], off));
        }
      }
      if (fr == 0) {
        #pragma unroll
        for (int r2 = 0; r2 < 4; ++r2) {
          pmax[j][wv][i * 16 + kb * 4 + r2] = mx[r2];
          pmin[j][wv][i * 16 + kb * 4 + r2] = mn[r2];
        }
      }
    }
  }
  __syncthreads();

  float lmax = -3.0e38f;  // only tid 0's copy is used
  #pragma unroll 1
  for (int s5 = 0; s5 < NS; ++s5) {
    if (tid < NB) {
      float mx = fmaxf(fmaxf(pmax[s5][0][tid], pmax[s5][1][tid]),
                       fmaxf(pmax[s5][2][tid], pmax[s5][3][tid]));
      float mn = fminf(fminf(pmin[s5][0][tid], pmin[s5][1][tid]),
                       fminf(pmin[s5][2][tid], pmin[s5][3][tid]));
      float qa = att[tid];
      pol[tid] = (qa >= 0.f) ? qa * mx : qa * mn;
    }
    __syncthreads();
    if (tid < NK * 8) {
      int k = tid >> 3, np0 = tid & 7;
      double cur = 1.0;                       // replicate _kernel_mus in double
      if (k >= 1) {
        double bq = 1.0 / (double)(NK - 1);
        cur = 1.0 - bq * 0.5;
        for (int i2 = 1; i2 < k; ++i2) cur -= bq;
      }
      float mu = (float)cur;
      float sig = (k == 0) ? 0.001f : 0.1f;
      float s2 = sig * sig;
      float a = 0.f;
      for (int n = np0; n < NB; n += 8) {
        float dd = pol[n] - mu;
        float x = dd * dd / s2 * 0.5f;
        a += msk[n] * fmaxf(-x, LOGMIN);      // log(clip(exp(-x),1e-30)) == max(-x, ln 1e-30)
      }
      a += __shfl_xor(a, 1);
      a += __shfl_xor(a, 2);
      a += __shfl_xor(a, 4);
      if (np0 == 0) te[k] = a;
    }
    __syncthreads();
    float y = 0.f;
    if (tid < PROJ) {
      float h = d1b[tid];
      #pragma unroll
      for (int k = 0; k < NK; ++k) h += te[k] * d1w[tid * NK + k];
      y = h * d2w[tid];
    }
    #pragma unroll
    for (int off = 1; off < 64; off <<= 1) y += __shfl_xor(y, off);
    if ((tid & 63) == 0) wred[tid >> 6] = y;
    __syncthreads();
    if (tid == 0) {
      float logit = wred[0] + wred[1] + wred[2] + wred[3] + d2b[0];
      lmax = fmaxf(lmax, logit);  // max_s sigmoid(x) == sigmoid(max_s x)
    }
  }
  if (tid == 0) out[q] = 1.0f / (1.0f + expf(-lmax));
}

extern "C" void kernel_launch(void* const* d_in, const int* in_sizes, int n_in,
                              void* d_out, int out_size, void* d_ws, size_t ws_size,
                              hipStream_t stream) {
  const int* sh   = (const int*)d_in[0];
  const int* qh   = (const int*)d_in[1];
  const int* st   = (const int*)d_in[2];
  const int* qt   = (const int*)d_in[3];
  const int* ed   = (const int*)d_in[4];
  // d_in[5] = edge_nums (unused by the reference computation)
  const float* rel = (const float*)d_in[6];
  const float* ent = (const float*)d_in[7];
  const float* aw  = (const float*)d_in[8];
  const float* ab  = (const float*)d_in[9];
  const float* d1w = (const float*)d_in[10];
  const float* d1b = (const float*)d_in[11];
  const float* d2w = (const float*)d_in[12];
  const float* d2b = (const float*)d_in[13];
  float* out = (float*)d_out;

  float* ws   = (float*)d_ws;
  float* wT   = ws;                 // 65,536 f
  float* t2   = wT + 65536;         // 1029*256 = 263,424 f
  float* qatt = t2 + 263424;        // 65,536 f
  unsigned short* Bb = (unsigned short*)(qatt + 65536);  // 320*256 bf16 = 160 KB (16B-aligned)

  k_transpose<<<DD, DD, 0, stream>>>(aw, wT);
  k_t2<<<NQ + NS, DD, 0, stream>>>(qh, qt, sh, st, ent, wT, ab, t2);
  k_qatt<<<NQ, DD, 0, stream>>>(qt, ed, ent, t2, qatt);
  k_support<<<NS, DD, 0, stream>>>(st, ed, ent, rel, t2, Bb);
  k_main<<<NQ, DD, 0, stream>>>(qt, ed, rel, Bb, qatt, d1w, d1b, d2w, d2b, out);
}